// Round 1
// baseline (347.471 us; speedup 1.0000x reference)
//
#include <hip/hip_runtime.h>
#include <hip/hip_bf16.h>

#define NY   512
#define NX   512
#define NXY  (NX * NY)        // 262144
#define T_DIM 64
#define DX_INV 10.0f          // 1/0.1
#define DX_INV_HALF 5.0f      // 0.5/0.1

// One wave (64 lanes) handles one full row of 512 elements:
//   segment A: j = 4*lane       (j in [0,256))
//   segment B: j = 256 + 4*lane (j in [256,512))
// Stencil neighbors come from __shfl within the wave — no redundant global loads.
// Block = 256 threads = 4 waves = 4 rows. Grid = 64 t * 128 row-groups = 8192 blocks.
__global__ __launch_bounds__(256) void gamma_reduce_kernel(
    const float* __restrict__ x, float* __restrict__ gsum) {
    const int wave = threadIdx.x >> 6;
    const int lane = threadIdx.x & 63;
    const int t    = blockIdx.x >> 7;    // 0..63
    const int rg   = blockIdx.x & 127;   // 0..127
    const int row  = (rg << 2) + wave;   // 0..511

    // x[0, 0, t, v, row, :]: offset = t*2*NXY + v*NXY + row*NY
    const float* nrow   = x + (size_t)t * (2 * NXY) + (size_t)row * NY;
    const float* phirow = nrow + NXY;

    const float4 pa = ((const float4*)phirow)[lane];
    const float4 pb = ((const float4*)phirow)[64 + lane];
    const float4 na = ((const float4*)nrow)[lane];
    const float4 nb = ((const float4*)nrow)[64 + lane];

    // Neighbor exchange (wave-wide shuffles, width 64 on CDNA)
    float pm_a = __shfl_up(pa.w, 1);     // phi[j0-1]; lane 0 unused (j==0 boundary)
    float pp_a = __shfl_down(pa.x, 1);   // phi[j0+4]; lane 63 patched below
    float pm_b = __shfl_up(pb.w, 1);     // lane 0 patched below
    float pp_b = __shfl_down(pb.x, 1);   // lane 63 unused (j==511 boundary)
    const float b0x  = __shfl(pb.x, 0);  // phi[256]
    const float a63w = __shfl(pa.w, 63); // phi[255]
    if (lane == 63) pp_a = b0x;
    if (lane == 0)  pm_b = a63w;

    // Segment A (j = 4*lane .. 4*lane+3)
    float gy0 = (lane == 0) ? (pa.y - pa.x) * DX_INV : (pa.y - pm_a) * DX_INV_HALF;
    float gy1 = (pa.z - pa.x) * DX_INV_HALF;
    float gy2 = (pa.w - pa.y) * DX_INV_HALF;
    float gy3 = (pp_a - pa.z) * DX_INV_HALF;
    float s = na.x * gy0 + na.y * gy1 + na.z * gy2 + na.w * gy3;

    // Segment B (j = 256 + 4*lane .. +3)
    gy0 = (pb.y - pm_b) * DX_INV_HALF;
    gy1 = (pb.z - pb.x) * DX_INV_HALF;
    gy2 = (pb.w - pb.y) * DX_INV_HALF;
    gy3 = (lane == 63) ? (pb.w - pb.z) * DX_INV : (pp_b - pb.z) * DX_INV_HALF;
    s += nb.x * gy0 + nb.y * gy1 + nb.z * gy2 + nb.w * gy3;

    // Wave reduce (64 lanes)
    #pragma unroll
    for (int off = 32; off > 0; off >>= 1) s += __shfl_down(s, off);

    __shared__ float wsum[4];
    if (lane == 0) wsum[wave] = s;
    __syncthreads();
    if (threadIdx.x == 0) {
        atomicAdd(&gsum[t], wsum[0] + wsum[1] + wsum[2] + wsum[3]);
    }
}

// feats: c0 = input_derived[t], c1 = gamma[t] = -sum/NXY
// h[hi] = gelu_tanh(w1[hi][0]*f0 + w1[hi][1]*f1 + b1[hi])
// out[t] = b2 + sum_hi w2[hi]*h[hi]
__global__ void mlp_kernel(const float* __restrict__ gsum,
                           const float* __restrict__ idv,
                           const float* __restrict__ w1,
                           const float* __restrict__ b1,
                           const float* __restrict__ w2,
                           const float* __restrict__ b2,
                           float* __restrict__ out) {
    const int t = threadIdx.x;
    if (t >= T_DIM) return;
    const float gamma = -gsum[t] * (1.0f / (float)NXY);
    const float f0 = idv[t];
    const float f1 = gamma;
    float o = b2[0];
    #pragma unroll
    for (int h = 0; h < 4; ++h) {
        const float z = w1[2 * h] * f0 + w1[2 * h + 1] * f1 + b1[h];
        // jax.nn.gelu default: tanh approximation
        const float inner = 0.7978845608028654f * (z + 0.044715f * z * z * z);
        const float g = 0.5f * z * (1.0f + tanhf(inner));
        o += w2[h] * g;
    }
    out[t] = o;
}

extern "C" void kernel_launch(void* const* d_in, const int* in_sizes, int n_in,
                              void* d_out, int out_size, void* d_ws, size_t ws_size,
                              hipStream_t stream) {
    const float* x   = (const float*)d_in[0];
    const float* idv = (const float*)d_in[1];
    const float* w1  = (const float*)d_in[2];
    const float* b1  = (const float*)d_in[3];
    const float* w2  = (const float*)d_in[4];
    const float* b2  = (const float*)d_in[5];
    float* out  = (float*)d_out;
    float* gsum = (float*)d_ws;   // 64 floats of scratch

    hipMemsetAsync(gsum, 0, T_DIM * sizeof(float), stream);
    gamma_reduce_kernel<<<T_DIM * 128, 256, 0, stream>>>(x, gsum);
    mlp_kernel<<<1, 64, 0, stream>>>(gsum, idv, w1, b1, w2, b2, out);
}

// Round 2
// 320.948 us; speedup vs baseline: 1.0826x; 1.0826x over previous
//
#include <hip/hip_runtime.h>
#include <hip/hip_bf16.h>

#define NY   512
#define NX   512
#define NXY  (NX * NY)        // 262144
#define T_DIM 64
#define DX_INV 10.0f          // 1/0.1
#define DX_INV_HALF 5.0f      // 0.5/0.1

typedef float f32x4 __attribute__((ext_vector_type(4)));

// Stage 1: one wave (64 lanes) per row of 512 elements, split as two
// 256-element segments (lane L covers j=4L and j=256+4L). Stencil neighbors
// via wave shuffles — zero redundant global loads. Block = 4 waves = 4 rows.
// Grid = 64 t * 128 row-groups. Each block writes ONE partial sum (no atomics,
// no workspace init needed): partial[rg*64 + t].
__global__ __launch_bounds__(256) void gamma_reduce_kernel(
    const float* __restrict__ x, float* __restrict__ partial) {
    const int wave = threadIdx.x >> 6;
    const int lane = threadIdx.x & 63;
    const int t    = blockIdx.x >> 7;    // 0..63
    const int rg   = blockIdx.x & 127;   // 0..127
    const int row  = (rg << 2) + wave;   // 0..511

    // x[0, 0, t, v, row, :]: offset = t*2*NXY + v*NXY + row*NY
    const float* nrow   = x + (size_t)t * (2 * NXY) + (size_t)row * NY;
    const float* phirow = nrow + NXY;

    const f32x4 pa = __builtin_nontemporal_load(((const f32x4*)phirow) + lane);
    const f32x4 pb = __builtin_nontemporal_load(((const f32x4*)phirow) + 64 + lane);
    const f32x4 na = __builtin_nontemporal_load(((const f32x4*)nrow) + lane);
    const f32x4 nb = __builtin_nontemporal_load(((const f32x4*)nrow) + 64 + lane);

    // Neighbor exchange (wave-wide shuffles, width 64 on CDNA)
    float pm_a = __shfl_up(pa.w, 1);     // phi[j0-1]; lane 0 unused (j==0 boundary)
    float pp_a = __shfl_down(pa.x, 1);   // phi[j0+4]; lane 63 patched below
    float pm_b = __shfl_up(pb.w, 1);     // lane 0 patched below
    float pp_b = __shfl_down(pb.x, 1);   // lane 63 unused (j==511 boundary)
    const float b0x  = __shfl(pb.x, 0);  // phi[256]
    const float a63w = __shfl(pa.w, 63); // phi[255]
    if (lane == 63) pp_a = b0x;
    if (lane == 0)  pm_b = a63w;

    // Segment A (j = 4*lane .. 4*lane+3)
    float gy0 = (lane == 0) ? (pa.y - pa.x) * DX_INV : (pa.y - pm_a) * DX_INV_HALF;
    float gy1 = (pa.z - pa.x) * DX_INV_HALF;
    float gy2 = (pa.w - pa.y) * DX_INV_HALF;
    float gy3 = (pp_a - pa.z) * DX_INV_HALF;
    float s = na.x * gy0 + na.y * gy1 + na.z * gy2 + na.w * gy3;

    // Segment B (j = 256 + 4*lane .. +3)
    gy0 = (pb.y - pm_b) * DX_INV_HALF;
    gy1 = (pb.z - pb.x) * DX_INV_HALF;
    gy2 = (pb.w - pb.y) * DX_INV_HALF;
    gy3 = (lane == 63) ? (pb.w - pb.z) * DX_INV : (pp_b - pb.z) * DX_INV_HALF;
    s += nb.x * gy0 + nb.y * gy1 + nb.z * gy2 + nb.w * gy3;

    // Wave reduce (64 lanes)
    #pragma unroll
    for (int off = 32; off > 0; off >>= 1) s += __shfl_down(s, off);

    __shared__ float wsum[4];
    if (lane == 0) wsum[wave] = s;
    __syncthreads();
    if (threadIdx.x == 0) {
        partial[(rg << 6) + t] = wsum[0] + wsum[1] + wsum[2] + wsum[3];
    }
}

// Stage 2: reduce 128 partials per t (coalesced: partial[i*64+t]) + MLP.
// One block, 256 threads = 4 quarters of the i-range per t.
__global__ __launch_bounds__(256) void stage2_kernel(
    const float* __restrict__ partial,
    const float* __restrict__ idv,
    const float* __restrict__ w1,
    const float* __restrict__ b1,
    const float* __restrict__ w2,
    const float* __restrict__ b2,
    float* __restrict__ out) {
    __shared__ float red[4][T_DIM];
    const int tid = threadIdx.x;
    const int t = tid & 63;
    const int q = tid >> 6;
    float s = 0.0f;
    #pragma unroll
    for (int i = 0; i < 32; ++i) {
        s += partial[((q * 32 + i) << 6) + t];
    }
    red[q][t] = s;
    __syncthreads();
    if (tid < T_DIM) {
        const float sum = red[0][t] + red[1][t] + red[2][t] + red[3][t];
        const float gamma = -sum * (1.0f / (float)NXY);
        const float f0 = idv[t];
        const float f1 = gamma;
        float o = b2[0];
        #pragma unroll
        for (int h = 0; h < 4; ++h) {
            const float z = w1[2 * h] * f0 + w1[2 * h + 1] * f1 + b1[h];
            // jax.nn.gelu default: tanh approximation
            const float inner = 0.7978845608028654f * (z + 0.044715f * z * z * z);
            const float g = 0.5f * z * (1.0f + tanhf(inner));
            o += w2[h] * g;
        }
        out[t] = o;
    }
}

extern "C" void kernel_launch(void* const* d_in, const int* in_sizes, int n_in,
                              void* d_out, int out_size, void* d_ws, size_t ws_size,
                              hipStream_t stream) {
    const float* x   = (const float*)d_in[0];
    const float* idv = (const float*)d_in[1];
    const float* w1  = (const float*)d_in[2];
    const float* b1  = (const float*)d_in[3];
    const float* w2  = (const float*)d_in[4];
    const float* b2  = (const float*)d_in[5];
    float* out     = (float*)d_out;
    float* partial = (float*)d_ws;   // 8192 floats of scratch, fully written by stage 1

    gamma_reduce_kernel<<<T_DIM * 128, 256, 0, stream>>>(x, partial);
    stage2_kernel<<<1, 256, 0, stream>>>(partial, idv, w1, b1, w2, b2, out);
}